// Round 2
// baseline (1412.049 us; speedup 1.0000x reference)
//
#include <hip/hip_runtime.h>

#define V 32000
#define E 65
#define H 65
#define B 8
#define T 512
#define G4 260        // 4*H
#define ROWS 4096     // B*T
#define SP 96         // padded K stride (16B-aligned bf16 rows)
#define NTILE 17      // ceil(260/16) gate tiles

typedef __bf16 bf16x8 __attribute__((ext_vector_type(8)));
typedef float f32x4 __attribute__((ext_vector_type(4)));
typedef unsigned short u16;
typedef unsigned int u32;

#define MFMA16 __builtin_amdgcn_mfma_f32_16x16x32_bf16

__device__ __forceinline__ float b2f(u16 u){ union{u32 u; float f;} v; v.u = ((u32)u)<<16; return v.f; }
__device__ __forceinline__ u16 f2b(float f){ union{float f; u32 u;} v; v.f = f; u32 r = v.u + 0x7FFFu + ((v.u>>16)&1u); return (u16)(r>>16); }
__device__ __forceinline__ float fsig(float x){ return 1.f/(1.f+__expf(-x)); }
__device__ __forceinline__ float ftanh(float x){ float e = __expf(2.f*x); return 1.f - 2.f/(e+1.f); }

// ---------------- K1: x-gates = emb[ids] @ w_ih.T + (b_ih+b_hh), MFMA, C-frag layout ----------
// xgc layout: t*2176 + tile*128 + lane*4 + reg   (lanes 0..31 only; lanes>=32 implicit zero)
__global__ __launch_bounds__(576) void k_embed(const int* __restrict__ ids,
        const float* __restrict__ emb, const float* __restrict__ wih,
        const float* __restrict__ bih, const float* __restrict__ bhh,
        float* __restrict__ xgc)
{
    __shared__ __align__(16) u16 wsh[272*SP];   // 52,224 B, zero-padded
    __shared__ __align__(16) u16 xrow[16*SP];   //  3,072 B
    const int t = blockIdx.x, tid = threadIdx.x, lane = tid&63, wv = tid>>6;
    const int col = lane&15, qd = lane>>4;
    for (int e = tid; e < 272*SP; e += 576){ int r = e/SP, c = e - r*SP;
        wsh[e] = (r < G4 && c < E) ? f2b(wih[r*E+c]) : (u16)0; }
    for (int e = tid; e < 16*SP; e += 576){ int r = e/SP, c = e - r*SP;
        u16 v = 0;
        if (r < B && c < E){ int id = ids[r*T+t]; v = f2b(emb[id*E+c]); }
        xrow[e] = v; }
    __syncthreads();
    bf16x8 a0 = *(const bf16x8*)&xrow[col*SP +  0 + qd*8];
    bf16x8 a1 = *(const bf16x8*)&xrow[col*SP + 32 + qd*8];
    bf16x8 a2 = *(const bf16x8*)&xrow[col*SP + 64 + qd*8];
    for (int tt = 0; tt < 2; ++tt){
        int tile = 2*wv + tt;
        if (tile >= NTILE) break;
        int r = tile*16 + col;
        bf16x8 b0 = *(const bf16x8*)&wsh[r*SP +  0 + qd*8];
        bf16x8 b1 = *(const bf16x8*)&wsh[r*SP + 32 + qd*8];
        bf16x8 b2 = *(const bf16x8*)&wsh[r*SP + 64 + qd*8];
        f32x4 acc = {0.f,0.f,0.f,0.f};
        acc = MFMA16(a0,b0,acc,0,0,0);
        acc = MFMA16(a1,b1,acc,0,0,0);
        acc = MFMA16(a2,b2,acc,0,0,0);
        if (lane < 32){
            int g = tile*16 + col;
            float bias = (g < G4) ? (bih[g] + bhh[g]) : 0.f;
            #pragma unroll
            for (int i = 0; i < 4; ++i)
                xgc[t*2176 + tile*128 + lane*4 + i] = acc[i] + bias;
        }
    }
}

// ---------------- K2: sequential LSTM, single workgroup, MFMA with split-h compensation -------
__global__ __launch_bounds__(576) void k_lstm(const float* __restrict__ whh_g,
    const float* __restrict__ h0g, const float* __restrict__ c0g,
    const float* __restrict__ xgc, u16* __restrict__ enc16,
    float* __restrict__ enc32, float* __restrict__ tail)
{
    __shared__ __align__(16) u16 whh[G4*SP];    // 49,920 B
    __shared__ __align__(16) u16 hhi[16*SP];    //  3,072 B
    __shared__ __align__(16) u16 hlo[16*SP];    //  3,072 B
    __shared__ float gates[B*G4];               //  8,320 B  (total 64,384 B)
    const int tid = threadIdx.x, lane = tid&63, wv = tid>>6;
    const int col = lane&15, qd = lane>>4;
    for (int e = tid; e < G4*SP; e += 576){ int r = e/SP, c = e - r*SP;
        whh[e] = (c < E) ? f2b(whh_g[r*E+c]) : (u16)0; }
    for (int e = tid; e < 16*SP; e += 576){ int r = e/SP, c = e - r*SP;
        u16 hi = 0, lo = 0;
        if (r < B && c < E){ float v = h0g[r*E+c]; hi = f2b(v); lo = f2b(v - b2f(hi)); }
        hhi[e] = hi; hlo[e] = lo; }
    // zero enc16 pad cols 65..95 (once)
    for (int e = tid; e < ROWS*(SP-E); e += 576){
        int r = e/(SP-E), c = E + (e - r*(SP-E));
        enc16[r*SP + c] = 0;
    }
    __syncthreads();

    const int tA = 2*wv, tB = 2*wv+1;
    const bool vB = (tB < NTILE);
    int rA = tA*16 + col; if (rA >= G4) rA = G4-1;   // clamp (cols>=4 of tile16 unused)
    int rB = vB ? (tB*16 + col) : rA;
    bf16x8 bfA[3], bfB[3];
    #pragma unroll
    for (int ch = 0; ch < 3; ++ch){
        bfA[ch] = *(const bf16x8*)&whh[rA*SP + ch*32 + qd*8];
        bfB[ch] = *(const bf16x8*)&whh[rB*SP + ch*32 + qd*8];
    }
    const bool ew = (tid < B*E);
    const int eb = tid/E, ej = tid - eb*E;
    float cst = ew ? c0g[eb*E+ej] : 0.f;

    const float* pA = xgc + tA*128 + lane*4;
    const float* pB = xgc + (vB ? tB : tA)*128 + lane*4;
    const f32x4 z4 = {0.f,0.f,0.f,0.f};
    f32x4 xc0 = (lane < 32) ? *(const f32x4*)pA : z4;
    f32x4 xc1 = (lane < 32) ? *(const f32x4*)pB : z4;

    for (int t = 0; t < T; ++t){
        bf16x8 h0a = *(const bf16x8*)&hhi[col*SP +  0 + qd*8];
        bf16x8 h1a = *(const bf16x8*)&hhi[col*SP + 32 + qd*8];
        bf16x8 h2a = *(const bf16x8*)&hhi[col*SP + 64 + qd*8];
        bf16x8 l0a = *(const bf16x8*)&hlo[col*SP +  0 + qd*8];
        bf16x8 l1a = *(const bf16x8*)&hlo[col*SP + 32 + qd*8];
        bf16x8 l2a = *(const bf16x8*)&hlo[col*SP + 64 + qd*8];
        f32x4 acc0 = xc0;
        acc0 = MFMA16(h0a, bfA[0], acc0, 0,0,0);
        acc0 = MFMA16(h1a, bfA[1], acc0, 0,0,0);
        acc0 = MFMA16(h2a, bfA[2], acc0, 0,0,0);
        acc0 = MFMA16(l0a, bfA[0], acc0, 0,0,0);
        acc0 = MFMA16(l1a, bfA[1], acc0, 0,0,0);
        acc0 = MFMA16(l2a, bfA[2], acc0, 0,0,0);
        f32x4 acc1 = xc1;
        if (vB){
            acc1 = MFMA16(h0a, bfB[0], acc1, 0,0,0);
            acc1 = MFMA16(h1a, bfB[1], acc1, 0,0,0);
            acc1 = MFMA16(h2a, bfB[2], acc1, 0,0,0);
            acc1 = MFMA16(l0a, bfB[0], acc1, 0,0,0);
            acc1 = MFMA16(l1a, bfB[1], acc1, 0,0,0);
            acc1 = MFMA16(l2a, bfB[2], acc1, 0,0,0);
        }
        int tn = (t < T-1) ? t+1 : t;     // prefetch next C-init
        if (lane < 32){
            xc0 = *(const f32x4*)(pA + (size_t)tn*2176);
            xc1 = *(const f32x4*)(pB + (size_t)tn*2176);
        }
        if (lane < 32){
            int g = tA*16 + col;
            if (g < G4){
                #pragma unroll
                for (int i = 0; i < 4; ++i) gates[(qd*4+i)*G4 + g] = acc0[i];
            }
            if (vB){
                int g2 = tB*16 + col;
                #pragma unroll
                for (int i = 0; i < 4; ++i) gates[(qd*4+i)*G4 + g2] = acc1[i];
            }
        }
        __syncthreads();
        if (ew){
            float gi = gates[eb*G4 + ej];
            float gf = gates[eb*G4 + E + ej];
            float gg = gates[eb*G4 + 2*E + ej];
            float go = gates[eb*G4 + 3*E + ej];
            cst = fsig(gf)*cst + fsig(gi)*ftanh(gg);
            float h = fsig(go)*ftanh(cst);
            u16 hi16 = f2b(h);
            float hiv = b2f(hi16);
            hhi[eb*SP + ej] = hi16;
            hlo[eb*SP + ej] = f2b(h - hiv);
            enc16[(eb*T+t)*SP + ej] = hi16;
            enc32[(eb*T+t)*E + ej] = h;
            if (t == T-1){
                tail[eb*E+ej] = h;              // hT (f32)
                tail[B*E + eb*E+ej] = cst;      // cT (f32)
            }
        }
        __syncthreads();
    }
}

// ---------------- K3a: queries + s_on/s_off in full f32 (scores are softmax-sensitive) -------
__global__ __launch_bounds__(520) void k_attn(const float* __restrict__ enc32,
    const float* __restrict__ uw, const float* __restrict__ ub,
    const float* __restrict__ ww, const float* __restrict__ wb,
    const float* __restrict__ vw, const float* __restrict__ vb,
    float* __restrict__ q32, float* __restrict__ s_on, float* __restrict__ s_off)
{
    __shared__ float uwT[E*E], wwT[E*E];     // [k][n], 16,900 B each
    __shared__ float encr[B*E];
    __shared__ float son_l[520], soff_l[520];
    const int r0 = blockIdx.x*B, tid = threadIdx.x;
    for (int e = tid; e < E*E; e += 520){ int r = e/E, c = e - r*E;
        uwT[c*E+r] = uw[e]; wwT[c*E+r] = ww[e]; }
    for (int e = tid; e < B*E; e += 520) encr[e] = enc32[r0*E + e];
    __syncthreads();
    const int rl = tid/E, n = tid - rl*E;     // tid < 520 == B*E exactly
    float fq = ub[n], fk = wb[n];
    for (int k = 0; k < E; ++k){
        float ev = encr[rl*E+k];
        fq += ev*uwT[k*E+n];
        fk += ev*wwT[k*E+n];
    }
    q32[(r0+rl)*E + n] = fq;
    float vv = vw[n];
    son_l[tid]  = vv*ftanh(fq+fk);
    soff_l[tid] = vv*ftanh(fk);
    __syncthreads();
    if (tid < B){
        float a = vb[0], b = vb[0];
        for (int k = 0; k < E; ++k){ a += son_l[tid*E+k]; b += soff_l[tid*E+k]; }
        s_on[r0+tid] = a; s_off[r0+tid] = b;
    }
}

// ---------------- K3b: O(T*H) causal-softmax context via prefix + totals ----------------------
__global__ __launch_bounds__(128) void k_scan(const float* __restrict__ q32,
    const float* __restrict__ s_on, const float* __restrict__ s_off,
    u16* __restrict__ ctx16)
{
    __shared__ float so[T], sff[T], red[128];
    const int b = blockIdx.x, tid = threadIdx.x;
    for (int e = tid; e < T; e += 128){ so[e] = s_on[b*T+e]; sff[e] = s_off[b*T+e]; }
    __syncthreads();
    float lm = -1e30f;
    for (int e = tid; e < T; e += 128) lm = fmaxf(lm, fmaxf(so[e], sff[e]));
    red[tid] = lm; __syncthreads();
    for (int s = 64; s > 0; s >>= 1){ if (tid < s) red[tid] = fmaxf(red[tid], red[tid+s]); __syncthreads(); }
    const float m = red[0];
    if (tid < E){
        const float* qcol = q32 + (size_t)(b*T)*E + tid;
        float toff = 0.f, toffs = 0.f;
        for (int t = 0; t < T; ++t){
            float eo = __expf(sff[t]-m);
            toff  += eo * qcol[(size_t)t*E];
            toffs += eo;
        }
        u16* cc = ctx16 + (size_t)(b*T)*SP + tid;
        float aA=0.f, aP=0.f, aAs=0.f, aPs=0.f;
        for (int t = 0; t < T; ++t){
            float qv = qcol[(size_t)t*E];
            float en = __expf(so[t]-m), eo = __expf(sff[t]-m);
            aA += en*qv; aP += eo*qv; aAs += en; aPs += eo;
            float num = aA + toff - aP;
            float den = aAs + toffs - aPs;
            cc[(size_t)t*SP] = f2b(num/den);
        }
    } else if (tid < SP){
        u16* cc = ctx16 + (size_t)(b*T)*SP + tid;
        for (int t = 0; t < T; ++t) cc[(size_t)t*SP] = 0;
    }
}

// ---------------- K4a: z = enc@oh_w.T + ctx@oz_w.T + biases ----------------------------------
__global__ __launch_bounds__(64) void k_zmix(const u16* __restrict__ enc16, const u16* __restrict__ ctx16,
    const float* __restrict__ ohw, const float* __restrict__ ohb,
    const float* __restrict__ ozw, const float* __restrict__ ozb, u16* __restrict__ z16)
{
    __shared__ __align__(16) u16 hsd[SP*SP];
    __shared__ __align__(16) u16 zsd[SP*SP];
    const int mt = blockIdx.x, tid = threadIdx.x;
    const int col = tid&15, qd = tid>>4;
    for (int e = tid; e < SP*SP; e += 64){
        int r = e/SP, c = e - r*SP;
        bool in = (r < E && c < E);
        hsd[e] = in ? f2b(ohw[r*E+c]) : (u16)0;
        zsd[e] = in ? f2b(ozw[r*E+c]) : (u16)0;
    }
    __syncthreads();
    const int arow = mt*16 + col;
    bf16x8 ae0 = *(const bf16x8*)&enc16[arow*SP +  0 + qd*8];
    bf16x8 ae1 = *(const bf16x8*)&enc16[arow*SP + 32 + qd*8];
    bf16x8 ae2 = *(const bf16x8*)&enc16[arow*SP + 64 + qd*8];
    bf16x8 ac0 = *(const bf16x8*)&ctx16[arow*SP +  0 + qd*8];
    bf16x8 ac1 = *(const bf16x8*)&ctx16[arow*SP + 32 + qd*8];
    bf16x8 ac2 = *(const bf16x8*)&ctx16[arow*SP + 64 + qd*8];
    for (int nt = 0; nt < 6; ++nt){
        int n = nt*16 + col;
        float bias = (n < E) ? (ohb[n] + ozb[n]) : 0.f;
        bf16x8 bh0 = *(const bf16x8*)&hsd[n*SP +  0 + qd*8];
        bf16x8 bh1 = *(const bf16x8*)&hsd[n*SP + 32 + qd*8];
        bf16x8 bh2 = *(const bf16x8*)&hsd[n*SP + 64 + qd*8];
        bf16x8 bz0 = *(const bf16x8*)&zsd[n*SP +  0 + qd*8];
        bf16x8 bz1 = *(const bf16x8*)&zsd[n*SP + 32 + qd*8];
        bf16x8 bz2 = *(const bf16x8*)&zsd[n*SP + 64 + qd*8];
        f32x4 acc = {0.f,0.f,0.f,0.f};
        acc = MFMA16(ae0,bh0,acc,0,0,0); acc = MFMA16(ae1,bh1,acc,0,0,0); acc = MFMA16(ae2,bh2,acc,0,0,0);
        acc = MFMA16(ac0,bz0,acc,0,0,0); acc = MFMA16(ac1,bz1,acc,0,0,0); acc = MFMA16(ac2,bz2,acc,0,0,0);
        #pragma unroll
        for (int i = 0; i < 4; ++i) z16[(mt*16 + qd*4 + i)*SP + n] = f2b(acc[i] + bias);
    }
}

// ---------------- K4pre: ov_w f32 [32000][65] -> bf16 [32000][96] zero-padded ----------------
__global__ __launch_bounds__(256) void k_ovw(const float* __restrict__ ovw, u16* __restrict__ ovw2){
    int g = blockIdx.x*256 + threadIdx.x;
    if (g >= V*SP) return;
    int n = g/SP, c = g - n*SP;
    ovw2[g] = (c < E) ? f2b(ovw[n*E+c]) : (u16)0;
}

// ---------------- K4b: out(f32) = z @ ov_w.T + ov_b, LDS repack for coalesced stores ---------
__global__ __launch_bounds__(256) void k_logits(const u16* __restrict__ z16,
    const u16* __restrict__ ovw2, const float* __restrict__ ovb, float* __restrict__ out)
{
    __shared__ __align__(16) float ot[16*260];
    const int mt = blockIdx.x, nb = blockIdx.y*256;
    const int tid = threadIdx.x, wv = tid>>6, lane = tid&63;
    const int col = lane&15, qd = lane>>4;
    const int arow = mt*16 + col;
    bf16x8 a0 = *(const bf16x8*)&z16[arow*SP +  0 + qd*8];
    bf16x8 a1 = *(const bf16x8*)&z16[arow*SP + 32 + qd*8];
    bf16x8 a2 = *(const bf16x8*)&z16[arow*SP + 64 + qd*8];
    #pragma unroll
    for (int nt = 0; nt < 4; ++nt){
        int nl = wv*64 + nt*16 + col;
        int n = nb + nl;
        const u16* bp = ovw2 + (size_t)n*SP + qd*8;
        bf16x8 b0 = *(const bf16x8*)(bp);
        bf16x8 b1 = *(const bf16x8*)(bp+32);
        bf16x8 b2 = *(const bf16x8*)(bp+64);
        f32x4 acc = {0.f,0.f,0.f,0.f};
        acc = MFMA16(a0,b0,acc,0,0,0); acc = MFMA16(a1,b1,acc,0,0,0); acc = MFMA16(a2,b2,acc,0,0,0);
        float bias = ovb[n];
        #pragma unroll
        for (int i = 0; i < 4; ++i) ot[(qd*4+i)*260 + nl] = acc[i] + bias;
    }
    __syncthreads();
    const int row = tid>>4, cg = tid&15;
    const float* src = &ot[row*260 + cg*16];
    float* dst = out + (size_t)(mt*16+row)*V + nb + cg*16;
    #pragma unroll
    for (int v4 = 0; v4 < 4; ++v4)
        ((float4*)dst)[v4] = *(const float4*)(src + v4*4);
}

extern "C" void kernel_launch(void* const* d_in, const int* in_sizes, int n_in,
                              void* d_out, int out_size, void* d_ws, size_t ws_size,
                              hipStream_t stream)
{
    const int*   ids = (const int*)d_in[0];
    const float* h0  = (const float*)d_in[1];
    const float* c0  = (const float*)d_in[2];
    const float* emb = (const float*)d_in[3];
    const float* wih = (const float*)d_in[4];
    const float* whh = (const float*)d_in[5];
    const float* bih = (const float*)d_in[6];
    const float* bhh = (const float*)d_in[7];
    const float* uw  = (const float*)d_in[8];
    const float* ub_ = (const float*)d_in[9];
    const float* ww  = (const float*)d_in[10];
    const float* wb_ = (const float*)d_in[11];
    const float* vw  = (const float*)d_in[12];
    const float* vb_ = (const float*)d_in[13];
    const float* ozw = (const float*)d_in[14];
    const float* ozb = (const float*)d_in[15];
    const float* ohw = (const float*)d_in[16];
    const float* ohb = (const float*)d_in[17];
    const float* ovw = (const float*)d_in[18];
    const float* ovb = (const float*)d_in[19];

    char* ws = (char*)d_ws;
    float* xgc  = (float*)(ws);                 // 4,456,448 B  (512*17*128 f32)
    u16*   enc16= (u16*)  (ws + 4456448);       //   786,432 B
    float* enc32= (float*)(ws + 5242880);       // 1,064,960 B
    float* q32  = (float*)(ws + 6307840);       // 1,064,960 B
    float* s_on = (float*)(ws + 7372800);       //    16,384 B
    float* s_off= (float*)(ws + 7389184);       //    16,384 B
    u16*   ctx16= (u16*)  (ws + 7405568);       //   786,432 B
    u16*   z16  = (u16*)  (ws + 8192000);       //   786,432 B
    u16*   ovw2 = (u16*)  (ws + 8978432);       // 6,144,000 B  (total ~14.4 MB)
    float* out  = (float*)d_out;
    float* tail = out + (size_t)ROWS*V;         // hT (520) then cT (520), f32

    hipLaunchKernelGGL(k_ovw,   dim3(V*SP/256), dim3(256), 0, stream, ovw, ovw2);
    hipLaunchKernelGGL(k_embed, dim3(T),        dim3(576), 0, stream, ids, emb, wih, bih, bhh, xgc);
    hipLaunchKernelGGL(k_lstm,  dim3(1),        dim3(576), 0, stream, whh, h0, c0, xgc, enc16, enc32, tail);
    hipLaunchKernelGGL(k_attn,  dim3(ROWS/B),   dim3(520), 0, stream, enc32, uw, ub_, ww, wb_, vw, vb_, q32, s_on, s_off);
    hipLaunchKernelGGL(k_scan,  dim3(B),        dim3(128), 0, stream, q32, s_on, s_off, ctx16);
    hipLaunchKernelGGL(k_zmix,  dim3(ROWS/16),  dim3(64),  0, stream, enc16, ctx16, ohw, ohb, ozw, ozb, z16);
    hipLaunchKernelGGL(k_logits,dim3(ROWS/16, V/256), dim3(256), 0, stream, z16, ovw2, ovb, out);
}